// Round 7
// baseline (133.884 us; speedup 1.0000x reference)
//
#include <hip/hip_runtime.h>
#include <cstddef>

#define HOP 256
#define NSTFT 513
#define N_MELS 80
#define T_AUDIO 320000
#define NUM_FRAMES 1251
#define NBATCH 16
#define TOTAL_FRAMES (NBATCH * NUM_FRAMES)  // 20016 = 1251 blocks * 4 waves * 4 frames

// Slaney mel constants
#define LOGSTEP 0.06875177742094913f
#define MEL_MAX 45.24564047f
#define DF 15.625f

__device__ __forceinline__ int reflect_idx(int j) {
    j = (j < 0) ? -j : j;
    j = (j >= T_AUDIO) ? (2 * T_AUDIO - 2 - j) : j;
    return j;
}

// mel band index of bin k (self-consistent with weight table build)
__device__ __forceinline__ int m1_of(int k) {
    const float f = k * DF;
    const float mel = (f < 1000.f) ? (3.0f / 200.0f) * f
                                   : 15.0f + logf(f * 1e-3f) * (1.0f / LOGSTEP);
    return (int)floorf(mel * (81.0f / MEL_MAX));
}

__device__ __forceinline__ int swz(int k) {  // conflict-breaking LDS slot
    return (k & ~15) | ((k ^ (k >> 4)) & 15);
}

__device__ __forceinline__ float bperm(int addr, float v) {
    return __int_as_float(__builtin_amdgcn_ds_bpermute(addr, __float_as_int(v)));
}

// DPP cross-lane exchange (VALU pipe) for xor 1/2/8
#define DPP_XOR1 0xB1   // quad_perm [1,0,3,2]
#define DPP_XOR2 0x4E   // quad_perm [2,3,0,1]
#define DPP_XOR8 0x128  // row_ror:8
template<int CTRL>
__device__ __forceinline__ float dppf(float x) {
    return __int_as_float(__builtin_amdgcn_update_dpp(
        0, __float_as_int(x), CTRL, 0xF, 0xF, true));
}

template<class F>
__device__ __forceinline__ void cstage(float (&zr)[2][16], float (&zi)[2][16],
                                       float sg, float twr_, float twi_, F comm) {
    #pragma unroll
    for (int p = 0; p < 2; ++p) {
        #pragma unroll
        for (int r = 0; r < 16; ++r) {
            const float pr  = comm(zr[p][r]);
            const float pim = comm(zi[p][r]);
            const float qr = fmaf(sg, zr[p][r], pr);
            const float qi = fmaf(sg, zi[p][r], pim);
            zr[p][r] = fmaf(qr, twr_, -(qi * twi_));
            zi[p][r] = fmaf(qr, twi_, qi * twr_);
        }
    }
}

// 4 waves/block, 4 frames/wave (2 real-packed complex FFTs). Four-step
// 1024-pt FFT (16 regs x 64 lanes). Mel phase via PREFIX SUMS: even lane
// holds contiguous 16-bin chunk (k2=brev6(lane)<32); per (pair,frame):
// running products -> 32-chunk wave scan (bpermute+shfl_up) -> inclusive
// PS (float2 u,d) to LDS -> mel[m] from 3 PS reads at triangle boundaries.
__global__ __launch_bounds__(256, 5) void melspec_ps_kernel(
    const float* __restrict__ wav,     // 16 x 320000
    const float* __restrict__ window,  // 1024
    const float* __restrict__ fb,      // 513 x 80
    const float* __restrict__ cosT,    // 1024 x 513 (row1 = cos(2pi j/1024))
    const float* __restrict__ sinT,    // 1024 x 513 (row1 = -sin(2pi j/1024))
    float* __restrict__ out)           // 16 x 80 x 1251
{
    __shared__ float2 psb[4][512];         // 16 KB inclusive prefix sums (u,d)
    __shared__ float2 wtab[512];           // 4 KB  (0.5*wu, 0.5*wd) per bin
    __shared__ unsigned short ks[84];      // band boundaries

    const int tid = threadIdx.x;
    const int lane = tid & 63;
    const int w = tid >> 6;
    const int g0 = (blockIdx.x * 4 + w) * 4;

    const int BREV4[16] = {0,8,4,12,2,10,6,14,1,9,5,13,3,11,7,15};
    const int SIG[16]   = {0,1,3,2,7,6,5,4,15,14,13,12,11,10,9,8};
    const float W16R[8] = {1.0f, 0.92387953251128674f, 0.70710678118654752f, 0.38268343236508977f,
                           0.0f, -0.38268343236508977f, -0.70710678118654752f, -0.92387953251128674f};
    const float W16I[8] = {0.0f, -0.38268343236508977f, -0.70710678118654752f, -0.92387953251128674f,
                           -1.0f, -0.92387953251128674f, -0.70710678118654752f, -0.38268343236508977f};

    // ---- per-block weight + band tables ----
    if (tid == 0) { ks[81] = 512; ks[82] = 512; }  // benign-race init (same value)
    for (int k = tid; k <= 512; k += 256) {
        const int mc = m1_of(k);
        if (k <= 511) {
            const float wu = (mc >= 0 && mc <= 79) ? 0.5f * fb[k * N_MELS + mc] : 0.0f;
            const float wd = (mc >= 1 && mc <= 80) ? 0.5f * fb[k * N_MELS + mc - 1] : 0.0f;
            wtab[swz(k)] = make_float2(wu, wd);
        }
        if (k >= 1) {
            const int mp = m1_of(k - 1);
            for (int m = mp + 1; m <= mc; ++m) ks[m] = (unsigned short)k;
            if (k == 1) ks[0] = 1;
        }
    }
    __syncthreads();

    unsigned bf0, ff0, bf3;
    {
        const unsigned g = (unsigned)g0;
        bf0 = g / NUM_FRAMES; ff0 = g - bf0 * NUM_FRAMES;
        bf3 = (unsigned)(g0 + 3) / NUM_FRAMES;
    }

    // ---- window ----
    float win[16];
    #pragma unroll
    for (int r = 0; r < 16; ++r) win[r] = window[r * 64 + lane];

    // ---- load 4 frames (75%-overlap shared-chunk; interior fast path) ----
    float zr[2][16], zi[2][16];
    if (bf0 == bf3) {
        const float* wb = wav + (size_t)bf0 * T_AUDIO;
        const int base = (int)ff0 * HOP - 512;
        float ch[28];
        if (base >= 0 && base + 27 * 64 + 63 < T_AUDIO) {
            #pragma unroll
            for (int c = 0; c < 28; ++c)
                ch[c] = wb[base + c * 64 + lane];
        } else {
            #pragma unroll
            for (int c = 0; c < 28; ++c)
                ch[c] = wb[reflect_idx(base + c * 64 + lane)];
        }
        #pragma unroll
        for (int r = 0; r < 16; ++r) {
            zr[0][r] = ch[r]      * win[r];
            zi[0][r] = ch[r + 4]  * win[r];
            zr[1][r] = ch[r + 8]  * win[r];
            zi[1][r] = ch[r + 12] * win[r];
        }
    } else {
        #pragma unroll
        for (int fi = 0; fi < 4; ++fi) {
            const unsigned g = (unsigned)(g0 + fi);
            const unsigned bb = g / NUM_FRAMES;
            const unsigned ffr = g - bb * NUM_FRAMES;
            const float* wb = wav + (size_t)bb * T_AUDIO;
            const int base = (int)ffr * HOP - 512;
            #pragma unroll
            for (int r = 0; r < 16; ++r) {
                const float v = wb[reflect_idx(base + r * 64 + lane)] * win[r];
                if (fi == 0) zr[0][r] = v;
                else if (fi == 1) zi[0][r] = v;
                else if (fi == 2) zr[1][r] = v;
                else zi[1][r] = v;
            }
        }
    }

    const float* twc = cosT + NSTFT;  // row n=1
    const float* tws = sinT + NSTFT;

    // ---- cross twiddles: wk[k] = W_1024^(lane*k) via complex powers ----
    const float w1r = twc[lane];
    const float w1i = tws[lane];
    float wkr[16], wki[16];
    wkr[0] = 1.0f; wki[0] = 0.0f;
    #pragma unroll
    for (int k = 1; k < 16; ++k) {
        wkr[k] = wkr[k-1] * w1r - wki[k-1] * w1i;
        wki[k] = wkr[k-1] * w1i + wki[k-1] * w1r;
    }

    // ---- stage twiddles for cross-lane FFT ----
    float c64[6], s64[6];
    #pragma unroll
    for (int t = 0; t < 6; ++t) {
        const int half = 32 >> t;
        const bool hi = (lane & half) != 0;
        const int jj = (lane & (half - 1)) << (t + 4);
        c64[t] = hi ? twc[jj] : 1.0f;
        s64[t] = hi ? tws[jj] : 0.0f;
    }

    // ---- A) 16-pt DIF FFT in registers ----
    #define CBFLY(ar, ai, br, bi, wr, wi) { \
        const float _tr = (ar) - (br), _ti = (ai) - (bi); \
        (ar) += (br); (ai) += (bi); \
        (br) = _tr * (wr) - _ti * (wi); \
        (bi) = _tr * (wi) + _ti * (wr); }

    #pragma unroll
    for (int p = 0; p < 2; ++p) {
        #pragma unroll
        for (int q = 0; q < 8; ++q) CBFLY(zr[p][q], zi[p][q], zr[p][q+8], zi[p][q+8], W16R[q], W16I[q]);
        #pragma unroll
        for (int g = 0; g < 16; g += 8)
            #pragma unroll
            for (int q = 0; q < 4; ++q) CBFLY(zr[p][g+q], zi[p][g+q], zr[p][g+q+4], zi[p][g+q+4], W16R[2*q], W16I[2*q]);
        #pragma unroll
        for (int g = 0; g < 16; g += 4)
            #pragma unroll
            for (int q = 0; q < 2; ++q) CBFLY(zr[p][g+q], zi[p][g+q], zr[p][g+q+2], zi[p][g+q+2], W16R[4*q], W16I[4*q]);
        #pragma unroll
        for (int g = 0; g < 16; g += 2) CBFLY(zr[p][g], zi[p][g], zr[p][g+1], zi[p][g+1], 1.0f, 0.0f);
    }

    // ---- B) cross twiddle ----
    #pragma unroll
    for (int r = 1; r < 16; ++r) {
        const float c1 = wkr[BREV4[r]];
        const float s1 = wki[BREV4[r]];
        #pragma unroll
        for (int p = 0; p < 2; ++p) {
            const float xr = zr[p][r], xi = zi[p][r];
            zr[p][r] = xr * c1 - xi * s1;
            zi[p][r] = xr * s1 + xi * c1;
        }
    }

    // ---- C) 64-pt DIF FFT across lanes ----
    {
        float sg;
        sg = (lane & 32) ? -1.0f : 1.0f;
        cstage(zr, zi, sg, c64[0], s64[0], [](float v) { return __shfl_xor(v, 32); });
        sg = (lane & 16) ? -1.0f : 1.0f;
        cstage(zr, zi, sg, c64[1], s64[1], [](float v) { return __shfl_xor(v, 16); });
        sg = (lane & 8) ? -1.0f : 1.0f;
        cstage(zr, zi, sg, c64[2], s64[2], [](float v) { return dppf<DPP_XOR8>(v); });
        sg = (lane & 4) ? -1.0f : 1.0f;
        cstage(zr, zi, sg, c64[3], s64[3], [](float v) { return __shfl_xor(v, 4); });
        sg = (lane & 2) ? -1.0f : 1.0f;
        cstage(zr, zi, sg, c64[4], s64[4], [](float v) { return dppf<DPP_XOR2>(v); });
        sg = (lane & 1) ? -1.0f : 1.0f;
        cstage(zr, zi, sg, c64[5], s64[5], [](float v) { return dppf<DPP_XOR1>(v); });
    }

    // ---- per pair: separation + magnitude (regs), then prefix-sum mel ----
    const int k2c = (int)(__brev((unsigned)lane) >> 26);   // chunk id (valid bins if <32)
    const int lp0 = (int)(__brev((unsigned)((64 - k2c) & 63)) >> 26);
    const int k2m16 = (k2c & 31) * 16;                      // wtab-safe chunk base
    const int k2c4 = k2c << 2;                              // bpermute addr (bytes)

    #pragma unroll
    for (int p = 0; p < 2; ++p) {
        // separation + magnitude into registers (0.5 folded into wtab)
        float mgA[16], mgB[16];
        #pragma unroll
        for (int r = 0; r < 16; ++r) {
            float cx, cy;
            if (r == 0) { cx = __shfl(zr[p][0], lp0); cy = __shfl(zi[p][0], lp0); }
            else        { cx = __shfl_xor(zr[p][SIG[r]], 63); cy = __shfl_xor(zi[p][SIG[r]], 63); }
            const float a = zr[p][r], b = zi[p][r];
            mgA[r] = sqrtf((a + cx) * (a + cx) + (b - cy) * (b - cy));
            mgB[r] = sqrtf((b + cy) * (b + cy) + (a - cx) * (a - cx));
        }

        // one pass per frame of the pair
        auto mel_pass = [&](const float (&mg)[16], int fi) {
            // running chunk totals of products
            float ru = 0.f, rd = 0.f;
            #pragma unroll
            for (int k1 = 0; k1 < 16; ++k1) {
                const int r = BREV4[k1];
                const float2 wt = wtab[swz(k2m16 + k1)];
                ru = fmaf(mg[r], wt.x, ru);
                rd = fmaf(mg[r], wt.y, rd);
            }
            // 32-chunk exclusive scan via bpermute(to k2 order) + shfl_up
            float vu = bperm(k2c4, ru), vd = bperm(k2c4, rd);
            const float tu = vu, td = vd;
            #pragma unroll
            for (int s = 1; s <= 16; s <<= 1) {
                const float au = __shfl_up(vu, s);
                const float ad = __shfl_up(vd, s);
                if (lane >= s) { vu += au; vd += ad; }
            }
            const float eu = bperm(k2c4, vu - tu);
            const float ed = bperm(k2c4, vd - td);
            // write inclusive PS (recompute products; even lanes own bins)
            if (!(lane & 1)) {
                float pu = eu, pd = ed;
                #pragma unroll
                for (int k1 = 0; k1 < 16; ++k1) {
                    const int r = BREV4[k1];
                    const float2 wt = wtab[swz(k2m16 + k1)];
                    pu = fmaf(mg[r], wt.x, pu);
                    pd = fmaf(mg[r], wt.y, pd);
                    psb[w][swz(k2m16 + k1)] = make_float2(pu, pd);
                }
            }
            // 80 mel outputs from 3 PS reads each
            #pragma unroll
            for (int ii = 0; ii < 2; ++ii) {
                const int m = lane + 64 * ii;
                if (m < N_MELS) {
                    const int ka = ks[m], kb = ks[m + 1], kc = ks[m + 2];
                    const float2 Pa = psb[w][swz(ka - 1)];
                    const float2 Pb = psb[w][swz(kb - 1)];
                    const float2 Pc = psb[w][swz(kc - 1)];
                    const float mel = (Pb.x - Pa.x) + (Pc.y - Pb.y);
                    const unsigned g = (unsigned)(g0 + 2 * p + fi);
                    const unsigned bb = g / NUM_FRAMES;
                    const unsigned ff = g - bb * NUM_FRAMES;
                    out[((size_t)bb * N_MELS + m) * NUM_FRAMES + ff] = mel;
                }
            }
        };
        mel_pass(mgA, 0);
        mel_pass(mgB, 1);
    }
}

extern "C" void kernel_launch(void* const* d_in, const int* in_sizes, int n_in,
                              void* d_out, int out_size, void* d_ws, size_t ws_size,
                              hipStream_t stream) {
    const float* wav    = (const float*)d_in[0];
    const float* window = (const float*)d_in[1];
    const float* fb     = (const float*)d_in[2];
    const float* cosT   = (const float*)d_in[3];
    const float* sinT   = (const float*)d_in[4];
    float* out = (float*)d_out;

    const int blocks = TOTAL_FRAMES / 16;  // 1251: 4 waves/block, 4 frames/wave
    melspec_ps_kernel<<<blocks, 256, 0, stream>>>(wav, window, fb, cosT, sinT, out);
}

// Round 8
// 70.396 us; speedup vs baseline: 1.9019x; 1.9019x over previous
//
#include <hip/hip_runtime.h>
#include <cstddef>

#define HOP 256
#define NSTFT 513
#define N_MELS 80
#define T_AUDIO 320000
#define NUM_FRAMES 1251
#define NBATCH 16
#define TOTAL_FRAMES (NBATCH * NUM_FRAMES)  // 20016 = 1251 blocks * 4 waves * 4 frames

// Slaney mel constants
#define LOGSTEP 0.06875177742094913f
#define MEL_MAX 45.24564047f
#define DF 15.625f

__device__ __forceinline__ int reflect_idx(int j) {
    j = (j < 0) ? -j : j;
    j = (j >= T_AUDIO) ? (2 * T_AUDIO - 2 - j) : j;
    return j;
}

// mel band index of bin k (self-consistent with weight table build)
__device__ __forceinline__ int m1_of(int k) {
    const float f = k * DF;
    const float mel = (f < 1000.f) ? (3.0f / 200.0f) * f
                                   : 15.0f + logf(f * 1e-3f) * (1.0f / LOGSTEP);
    return (int)floorf(mel * (81.0f / MEL_MAX));
}

__device__ __forceinline__ int swz(int k) {  // conflict-breaking LDS slot
    return (k & ~15) | ((k ^ (k >> 4)) & 15);
}

__device__ __forceinline__ float bperm(int addr, float v) {
    return __int_as_float(__builtin_amdgcn_ds_bpermute(addr, __float_as_int(v)));
}

// DPP cross-lane exchange (VALU pipe) for xor 1/2/8
#define DPP_XOR1 0xB1   // quad_perm [1,0,3,2]
#define DPP_XOR2 0x4E   // quad_perm [2,3,0,1]
#define DPP_XOR8 0x128  // row_ror:8
template<int CTRL>
__device__ __forceinline__ float dppf(float x) {
    return __int_as_float(__builtin_amdgcn_update_dpp(
        0, __float_as_int(x), CTRL, 0xF, 0xF, true));
}

template<class F>
__device__ __forceinline__ void cstage(float (&zr)[2][16], float (&zi)[2][16],
                                       float sg, float twr_, float twi_, F comm) {
    #pragma unroll
    for (int p = 0; p < 2; ++p) {
        #pragma unroll
        for (int r = 0; r < 16; ++r) {
            const float pr  = comm(zr[p][r]);
            const float pim = comm(zi[p][r]);
            const float qr = fmaf(sg, zr[p][r], pr);
            const float qi = fmaf(sg, zi[p][r], pim);
            zr[p][r] = fmaf(qr, twr_, -(qi * twi_));
            zi[p][r] = fmaf(qr, twi_, qi * twr_);
        }
    }
}

// 4 waves/block, 4 frames/wave (2 real-packed complex FFTs). Four-step
// 1024-pt FFT (16 regs x 64 lanes). Mel via prefix sums, fused per pair:
// separation loop computes magnitudes AND per-bin weighted products for
// both frames (float4 -> LDS) + 4 chunk accumulators; one 4-component
// 32-chunk wave scan (bpermute + shfl_up); chunk-owner lanes rewrite the
// buffer in place as inclusive PS; mel[m] = 3 b128 PS reads at triangle
// boundaries for both frames. No register mg arrays -> no spill.
__global__ __launch_bounds__(256) void melspec_ps2_kernel(
    const float* __restrict__ wav,     // 16 x 320000
    const float* __restrict__ window,  // 1024
    const float* __restrict__ fb,      // 513 x 80
    const float* __restrict__ cosT,    // 1024 x 513 (row1 = cos(2pi j/1024))
    const float* __restrict__ sinT,    // 1024 x 513 (row1 = -sin(2pi j/1024))
    float* __restrict__ out)           // 16 x 80 x 1251
{
    __shared__ float4 sprod[4][512];       // 32 KB products -> inclusive PS (uA,dA,uB,dB)
    __shared__ float2 wtab[512];           // 4 KB (0.5*wu, 0.5*wd) per bin
    __shared__ unsigned short ks[84];      // band boundaries

    const int tid = threadIdx.x;
    const int lane = tid & 63;
    const int w = tid >> 6;
    const int g0 = (blockIdx.x * 4 + w) * 4;

    const int BREV4[16] = {0,8,4,12,2,10,6,14,1,9,5,13,3,11,7,15};
    const int SIG[16]   = {0,1,3,2,7,6,5,4,15,14,13,12,11,10,9,8};
    const float W16R[8] = {1.0f, 0.92387953251128674f, 0.70710678118654752f, 0.38268343236508977f,
                           0.0f, -0.38268343236508977f, -0.70710678118654752f, -0.92387953251128674f};
    const float W16I[8] = {0.0f, -0.38268343236508977f, -0.70710678118654752f, -0.92387953251128674f,
                           -1.0f, -0.92387953251128674f, -0.70710678118654752f, -0.38268343236508977f};

    // ---- per-block weight + band tables ----
    if (tid == 0) { ks[81] = 512; ks[82] = 512; }  // benign-race init (same value)
    for (int k = tid; k <= 512; k += 256) {
        const int mc = m1_of(k);
        if (k <= 511) {
            const float wu = (mc >= 0 && mc <= 79) ? 0.5f * fb[k * N_MELS + mc] : 0.0f;
            const float wd = (mc >= 1 && mc <= 80) ? 0.5f * fb[k * N_MELS + mc - 1] : 0.0f;
            wtab[swz(k)] = make_float2(wu, wd);
        }
        if (k >= 1) {
            const int mp = m1_of(k - 1);
            for (int m = mp + 1; m <= mc; ++m) ks[m] = (unsigned short)k;
            if (k == 1) ks[0] = 1;
        }
    }
    __syncthreads();

    unsigned bf0, ff0, bf3;
    {
        const unsigned g = (unsigned)g0;
        bf0 = g / NUM_FRAMES; ff0 = g - bf0 * NUM_FRAMES;
        bf3 = (unsigned)(g0 + 3) / NUM_FRAMES;
    }

    // ---- window ----
    float win[16];
    #pragma unroll
    for (int r = 0; r < 16; ++r) win[r] = window[r * 64 + lane];

    // ---- load 4 frames (75%-overlap shared-chunk; interior fast path) ----
    float zr[2][16], zi[2][16];
    if (bf0 == bf3) {
        const float* wb = wav + (size_t)bf0 * T_AUDIO;
        const int base = (int)ff0 * HOP - 512;
        float ch[28];
        if (base >= 0 && base + 27 * 64 + 63 < T_AUDIO) {
            #pragma unroll
            for (int c = 0; c < 28; ++c)
                ch[c] = wb[base + c * 64 + lane];
        } else {
            #pragma unroll
            for (int c = 0; c < 28; ++c)
                ch[c] = wb[reflect_idx(base + c * 64 + lane)];
        }
        #pragma unroll
        for (int r = 0; r < 16; ++r) {
            zr[0][r] = ch[r]      * win[r];
            zi[0][r] = ch[r + 4]  * win[r];
            zr[1][r] = ch[r + 8]  * win[r];
            zi[1][r] = ch[r + 12] * win[r];
        }
    } else {
        #pragma unroll
        for (int fi = 0; fi < 4; ++fi) {
            const unsigned g = (unsigned)(g0 + fi);
            const unsigned bb = g / NUM_FRAMES;
            const unsigned ffr = g - bb * NUM_FRAMES;
            const float* wb = wav + (size_t)bb * T_AUDIO;
            const int base = (int)ffr * HOP - 512;
            #pragma unroll
            for (int r = 0; r < 16; ++r) {
                const float v = wb[reflect_idx(base + r * 64 + lane)] * win[r];
                if (fi == 0) zr[0][r] = v;
                else if (fi == 1) zi[0][r] = v;
                else if (fi == 2) zr[1][r] = v;
                else zi[1][r] = v;
            }
        }
    }

    const float* twc = cosT + NSTFT;  // row n=1
    const float* tws = sinT + NSTFT;

    // ---- cross twiddles: wk[k] = W_1024^(lane*k) via complex powers ----
    const float w1r = twc[lane];
    const float w1i = tws[lane];
    float wkr[16], wki[16];
    wkr[0] = 1.0f; wki[0] = 0.0f;
    #pragma unroll
    for (int k = 1; k < 16; ++k) {
        wkr[k] = wkr[k-1] * w1r - wki[k-1] * w1i;
        wki[k] = wkr[k-1] * w1i + wki[k-1] * w1r;
    }

    // ---- stage twiddles for cross-lane FFT ----
    float c64[6], s64[6];
    #pragma unroll
    for (int t = 0; t < 6; ++t) {
        const int half = 32 >> t;
        const bool hi = (lane & half) != 0;
        const int jj = (lane & (half - 1)) << (t + 4);
        c64[t] = hi ? twc[jj] : 1.0f;
        s64[t] = hi ? tws[jj] : 0.0f;
    }

    // ---- A) 16-pt DIF FFT in registers ----
    #define CBFLY(ar, ai, br, bi, wr, wi) { \
        const float _tr = (ar) - (br), _ti = (ai) - (bi); \
        (ar) += (br); (ai) += (bi); \
        (br) = _tr * (wr) - _ti * (wi); \
        (bi) = _tr * (wi) + _ti * (wr); }

    #pragma unroll
    for (int p = 0; p < 2; ++p) {
        #pragma unroll
        for (int q = 0; q < 8; ++q) CBFLY(zr[p][q], zi[p][q], zr[p][q+8], zi[p][q+8], W16R[q], W16I[q]);
        #pragma unroll
        for (int g = 0; g < 16; g += 8)
            #pragma unroll
            for (int q = 0; q < 4; ++q) CBFLY(zr[p][g+q], zi[p][g+q], zr[p][g+q+4], zi[p][g+q+4], W16R[2*q], W16I[2*q]);
        #pragma unroll
        for (int g = 0; g < 16; g += 4)
            #pragma unroll
            for (int q = 0; q < 2; ++q) CBFLY(zr[p][g+q], zi[p][g+q], zr[p][g+q+2], zi[p][g+q+2], W16R[4*q], W16I[4*q]);
        #pragma unroll
        for (int g = 0; g < 16; g += 2) CBFLY(zr[p][g], zi[p][g], zr[p][g+1], zi[p][g+1], 1.0f, 0.0f);
    }

    // ---- B) cross twiddle ----
    #pragma unroll
    for (int r = 1; r < 16; ++r) {
        const float c1 = wkr[BREV4[r]];
        const float s1 = wki[BREV4[r]];
        #pragma unroll
        for (int p = 0; p < 2; ++p) {
            const float xr = zr[p][r], xi = zi[p][r];
            zr[p][r] = xr * c1 - xi * s1;
            zi[p][r] = xr * s1 + xi * c1;
        }
    }

    // ---- C) 64-pt DIF FFT across lanes ----
    {
        float sg;
        sg = (lane & 32) ? -1.0f : 1.0f;
        cstage(zr, zi, sg, c64[0], s64[0], [](float v) { return __shfl_xor(v, 32); });
        sg = (lane & 16) ? -1.0f : 1.0f;
        cstage(zr, zi, sg, c64[1], s64[1], [](float v) { return __shfl_xor(v, 16); });
        sg = (lane & 8) ? -1.0f : 1.0f;
        cstage(zr, zi, sg, c64[2], s64[2], [](float v) { return dppf<DPP_XOR8>(v); });
        sg = (lane & 4) ? -1.0f : 1.0f;
        cstage(zr, zi, sg, c64[3], s64[3], [](float v) { return __shfl_xor(v, 4); });
        sg = (lane & 2) ? -1.0f : 1.0f;
        cstage(zr, zi, sg, c64[4], s64[4], [](float v) { return dppf<DPP_XOR2>(v); });
        sg = (lane & 1) ? -1.0f : 1.0f;
        cstage(zr, zi, sg, c64[5], s64[5], [](float v) { return dppf<DPP_XOR1>(v); });
    }

    // ---- per pair: fused separation + products + scan + PS + mel ----
    const int k2c = (int)(__brev((unsigned)lane) >> 26);   // chunk id; bins valid if <32
    const int lp0 = (int)(__brev((unsigned)((64 - k2c) & 63)) >> 26);
    const bool hasbin = (k2c < 32);                         // == even lane
    const int k2m16 = (k2c & 31) * 16;
    const int k2c4 = k2c << 2;                              // bpermute addr (bytes)

    #pragma unroll
    for (int p = 0; p < 2; ++p) {
        // separation + magnitude + weighted products (LDS) + chunk totals (regs)
        float ruA = 0.f, rdA = 0.f, ruB = 0.f, rdB = 0.f;
        #pragma unroll
        for (int r = 0; r < 16; ++r) {
            float cx, cy;
            if (r == 0) { cx = __shfl(zr[p][0], lp0); cy = __shfl(zi[p][0], lp0); }
            else        { cx = __shfl_xor(zr[p][SIG[r]], 63); cy = __shfl_xor(zi[p][SIG[r]], 63); }
            const float a = zr[p][r], b = zi[p][r];
            const float magA = sqrtf((a + cx) * (a + cx) + (b - cy) * (b - cy));
            const float magB = sqrtf((b + cy) * (b + cy) + (a - cx) * (a - cx));
            if (hasbin) {
                const int sl = swz(k2m16 + BREV4[r]);
                const float2 wt = wtab[sl];
                const float puA = magA * wt.x, pdA = magA * wt.y;
                const float puB = magB * wt.x, pdB = magB * wt.y;
                ruA += puA; rdA += pdA; ruB += puB; rdB += pdB;
                sprod[w][sl] = make_float4(puA, pdA, puB, pdB);
            }
        }

        // 32-chunk exclusive scan of 4 components (chunks>=32 carry zeros)
        float vuA = bperm(k2c4, ruA), vdA = bperm(k2c4, rdA);
        float vuB = bperm(k2c4, ruB), vdB = bperm(k2c4, rdB);
        const float tuA = vuA, tdA = vdA, tuB = vuB, tdB = vdB;
        #pragma unroll
        for (int s = 1; s <= 16; s <<= 1) {
            const float auA = __shfl_up(vuA, s);
            const float adA = __shfl_up(vdA, s);
            const float auB = __shfl_up(vuB, s);
            const float adB = __shfl_up(vdB, s);
            if (lane >= s) { vuA += auA; vdA += adA; vuB += auB; vdB += adB; }
        }
        const float euA = bperm(k2c4, vuA - tuA);
        const float edA = bperm(k2c4, vdA - tdA);
        const float euB = bperm(k2c4, vuB - tuB);
        const float edB = bperm(k2c4, vdB - tdB);

        // in-place rewrite as inclusive prefix sums (chunk-owner lanes)
        if (hasbin) {
            float puA = euA, pdA = edA, puB = euB, pdB = edB;
            #pragma unroll
            for (int k1 = 0; k1 < 16; ++k1) {
                const int sl = swz(k2m16 + k1);
                const float4 pr = sprod[w][sl];
                puA += pr.x; pdA += pr.y; puB += pr.z; pdB += pr.w;
                sprod[w][sl] = make_float4(puA, pdA, puB, pdB);
            }
        }

        // 160 mel outputs (80 mels x 2 frames) from 3 PS reads each
        #pragma unroll
        for (int ii = 0; ii < 3; ++ii) {
            const int t2 = lane + 64 * ii;
            if (t2 < 2 * N_MELS) {
                const int m = t2 >> 1;
                const int fi = t2 & 1;
                const int ka = ks[m], kb = ks[m + 1], kc = ks[m + 2];
                const float4 Pa = sprod[w][swz(ka - 1)];
                const float4 Pb = sprod[w][swz(kb - 1)];
                const float4 Pc = sprod[w][swz(kc - 1)];
                const float mel = fi ? (Pb.z - Pa.z) + (Pc.w - Pb.w)
                                     : (Pb.x - Pa.x) + (Pc.y - Pb.y);
                const unsigned g = (unsigned)(g0 + 2 * p + fi);
                const unsigned bb = g / NUM_FRAMES;
                const unsigned ff = g - bb * NUM_FRAMES;
                out[((size_t)bb * N_MELS + m) * NUM_FRAMES + ff] = mel;
            }
        }
    }
}

extern "C" void kernel_launch(void* const* d_in, const int* in_sizes, int n_in,
                              void* d_out, int out_size, void* d_ws, size_t ws_size,
                              hipStream_t stream) {
    const float* wav    = (const float*)d_in[0];
    const float* window = (const float*)d_in[1];
    const float* fb     = (const float*)d_in[2];
    const float* cosT   = (const float*)d_in[3];
    const float* sinT   = (const float*)d_in[4];
    float* out = (float*)d_out;

    const int blocks = TOTAL_FRAMES / 16;  // 1251: 4 waves/block, 4 frames/wave
    melspec_ps2_kernel<<<blocks, 256, 0, stream>>>(wav, window, fb, cosT, sinT, out);
}

// Round 9
// 56.445 us; speedup vs baseline: 2.3719x; 1.2472x over previous
//
#include <hip/hip_runtime.h>
#include <cstddef>

#define HOP 256
#define NSTFT 513
#define N_MELS 80
#define T_AUDIO 320000
#define NUM_FRAMES 1251
#define NBATCH 16
#define TOTAL_FRAMES (NBATCH * NUM_FRAMES)  // 20016 = 1251 blocks * 4 waves * 4 frames

// Slaney mel constants
#define LOGSTEP 0.06875177742094913f
#define MEL_MAX 45.24564047f
#define DF 15.625f

__device__ __forceinline__ int reflect_idx(int j) {
    j = (j < 0) ? -j : j;
    j = (j >= T_AUDIO) ? (2 * T_AUDIO - 2 - j) : j;
    return j;
}

// mel band index of bin k (self-consistent with weight table build)
__device__ __forceinline__ int m1_of(int k) {
    const float f = k * DF;
    const float mel = (f < 1000.f) ? (3.0f / 200.0f) * f
                                   : 15.0f + logf(f * 1e-3f) * (1.0f / LOGSTEP);
    return (int)floorf(mel * (81.0f / MEL_MAX));
}

__device__ __forceinline__ int swz(int k) {  // conflict-breaking LDS slot
    return (k & ~15) | ((k ^ (k >> 4)) & 15);
}

// ---- semantics-robust permlane sums: s = v + v[lane^half] ----
// permlane*_swap returns {a', b'} where per lane the pair {a'[l], b'[l]} ==
// {v[l], v[l^half]} as a set (regardless of which operand convention the HW
// uses), so the float sum a'+b' is exactly v + partner.
__device__ __forceinline__ float plsum32(float v) {
#if __has_builtin(__builtin_amdgcn_permlane32_swap)
    auto r = __builtin_amdgcn_permlane32_swap(__float_as_int(v), __float_as_int(v), false, false);
    return __int_as_float(r[0]) + __int_as_float(r[1]);
#else
    return v + __shfl_xor(v, 32);
#endif
}
__device__ __forceinline__ float plsum16(float v) {
#if __has_builtin(__builtin_amdgcn_permlane16_swap)
    auto r = __builtin_amdgcn_permlane16_swap(__float_as_int(v), __float_as_int(v), false, false);
    return __int_as_float(r[0]) + __int_as_float(r[1]);
#else
    return v + __shfl_xor(v, 16);
#endif
}

// DPP cross-lane exchange (VALU pipe) for xor 1/2/8
#define DPP_XOR1 0xB1   // quad_perm [1,0,3,2]
#define DPP_XOR2 0x4E   // quad_perm [2,3,0,1]
#define DPP_XOR8 0x128  // row_ror:8
template<int CTRL>
__device__ __forceinline__ float dppf(float x) {
    return __int_as_float(__builtin_amdgcn_update_dpp(
        0, __float_as_int(x), CTRL, 0xF, 0xF, true));
}

// classic butterfly stage: partner fetched via comm (DS or DPP)
template<class F>
__device__ __forceinline__ void cstage(float (&zr)[2][16], float (&zi)[2][16],
                                       float sg, float twr_, float twi_, F comm) {
    #pragma unroll
    for (int p = 0; p < 2; ++p) {
        #pragma unroll
        for (int r = 0; r < 16; ++r) {
            const float pr  = comm(zr[p][r]);
            const float pim = comm(zi[p][r]);
            const float qr = fmaf(sg, zr[p][r], pr);
            const float qi = fmaf(sg, zi[p][r], pim);
            zr[p][r] = fmaf(qr, twr_, -(qi * twi_));
            zi[p][r] = fmaf(qr, twi_, qi * twr_);
        }
    }
}

// sum-form butterfly stage: sumf(v) = v + partner; q = fmaf(m2, v, s)
// (m2 = 0 on lo lanes -> q = sum; m2 = -2 on hi lanes -> q = partner - v)
template<class FS>
__device__ __forceinline__ void cstage_sum(float (&zr)[2][16], float (&zi)[2][16],
                                           float m2, float twr_, float twi_, FS sumf) {
    #pragma unroll
    for (int p = 0; p < 2; ++p) {
        #pragma unroll
        for (int r = 0; r < 16; ++r) {
            const float sR = sumf(zr[p][r]);
            const float sI = sumf(zi[p][r]);
            const float qr = fmaf(m2, zr[p][r], sR);
            const float qi = fmaf(m2, zi[p][r], sI);
            zr[p][r] = fmaf(qr, twr_, -(qi * twi_));
            zi[p][r] = fmaf(qr, twi_, qi * twr_);
        }
    }
}

// 4 waves/block, 4 frames/wave (2 real-packed complex FFTs). Four-step
// 1024-pt FFT (16 regs x 64 lanes): xor32/xor16 stages on the VALU via
// permlane swaps, xor8/2/1 via DPP, only xor4 on the DS pipe. Separation
// writes PRE-MULTIPLIED products (mag*wu, mag*wd) per frame into wave-
// private prodA/prodB (b64, swizzled); the triangle mel loop then does a
// single b64 read per bin. No barriers after table build (wave-private DS).
__global__ __launch_bounds__(256) void melspec_prod_kernel(
    const float* __restrict__ wav,     // 16 x 320000
    const float* __restrict__ window,  // 1024
    const float* __restrict__ fb,      // 513 x 80
    const float* __restrict__ cosT,    // 1024 x 513 (row1 = cos(2pi j/1024))
    const float* __restrict__ sinT,    // 1024 x 513 (row1 = -sin(2pi j/1024))
    float* __restrict__ out)           // 16 x 80 x 1251
{
    __shared__ float2 prodA[4][512];       // 16 KB (mag*wu, mag*wd) frame A of pair
    __shared__ float2 prodB[4][512];       // 16 KB frame B of pair
    __shared__ float2 wtab[512];           // 4 KB (0.5*wu, 0.5*wd) per bin
    __shared__ unsigned short ks[84];      // band boundaries

    const int tid = threadIdx.x;
    const int lane = tid & 63;
    const int w = tid >> 6;
    const int g0 = (blockIdx.x * 4 + w) * 4;

    const int BREV4[16] = {0,8,4,12,2,10,6,14,1,9,5,13,3,11,7,15};
    const int SIG[16]   = {0,1,3,2,7,6,5,4,15,14,13,12,11,10,9,8};
    const float W16R[8] = {1.0f, 0.92387953251128674f, 0.70710678118654752f, 0.38268343236508977f,
                           0.0f, -0.38268343236508977f, -0.70710678118654752f, -0.92387953251128674f};
    const float W16I[8] = {0.0f, -0.38268343236508977f, -0.70710678118654752f, -0.92387953251128674f,
                           -1.0f, -0.92387953251128674f, -0.70710678118654752f, -0.38268343236508977f};

    // ---- per-block weight + band tables ----
    if (tid == 0) { ks[81] = 512; ks[82] = 512; }  // benign-race init (same value)
    for (int k = tid; k <= 512; k += 256) {
        const int mc = m1_of(k);
        if (k <= 511) {
            const float wu = (mc >= 0 && mc <= 79) ? 0.5f * fb[k * N_MELS + mc] : 0.0f;
            const float wd = (mc >= 1 && mc <= 80) ? 0.5f * fb[k * N_MELS + mc - 1] : 0.0f;
            wtab[swz(k)] = make_float2(wu, wd);
        }
        if (k >= 1) {
            const int mp = m1_of(k - 1);
            for (int m = mp + 1; m <= mc; ++m) ks[m] = (unsigned short)k;
            if (k == 1) ks[0] = 1;
        }
    }
    __syncthreads();

    unsigned bf0, ff0, bf3;
    {
        const unsigned g = (unsigned)g0;
        bf0 = g / NUM_FRAMES; ff0 = g - bf0 * NUM_FRAMES;
        bf3 = (unsigned)(g0 + 3) / NUM_FRAMES;
    }

    // ---- window ----
    float win[16];
    #pragma unroll
    for (int r = 0; r < 16; ++r) win[r] = window[r * 64 + lane];

    // ---- load 4 frames (75%-overlap shared-chunk; interior fast path) ----
    float zr[2][16], zi[2][16];
    if (bf0 == bf3) {
        const float* wb = wav + (size_t)bf0 * T_AUDIO;
        const int base = (int)ff0 * HOP - 512;
        float ch[28];
        if (base >= 0 && base + 27 * 64 + 63 < T_AUDIO) {
            #pragma unroll
            for (int c = 0; c < 28; ++c)
                ch[c] = wb[base + c * 64 + lane];
        } else {
            #pragma unroll
            for (int c = 0; c < 28; ++c)
                ch[c] = wb[reflect_idx(base + c * 64 + lane)];
        }
        #pragma unroll
        for (int r = 0; r < 16; ++r) {
            zr[0][r] = ch[r]      * win[r];
            zi[0][r] = ch[r + 4]  * win[r];
            zr[1][r] = ch[r + 8]  * win[r];
            zi[1][r] = ch[r + 12] * win[r];
        }
    } else {
        #pragma unroll
        for (int fi = 0; fi < 4; ++fi) {
            const unsigned g = (unsigned)(g0 + fi);
            const unsigned bb = g / NUM_FRAMES;
            const unsigned ffr = g - bb * NUM_FRAMES;
            const float* wb = wav + (size_t)bb * T_AUDIO;
            const int base = (int)ffr * HOP - 512;
            #pragma unroll
            for (int r = 0; r < 16; ++r) {
                const float v = wb[reflect_idx(base + r * 64 + lane)] * win[r];
                if (fi == 0) zr[0][r] = v;
                else if (fi == 1) zi[0][r] = v;
                else if (fi == 2) zr[1][r] = v;
                else zi[1][r] = v;
            }
        }
    }

    const float* twc = cosT + NSTFT;  // row n=1
    const float* tws = sinT + NSTFT;

    // ---- cross twiddles: wk[k] = W_1024^(lane*k) via complex powers ----
    const float w1r = twc[lane];
    const float w1i = tws[lane];
    float wkr[16], wki[16];
    wkr[0] = 1.0f; wki[0] = 0.0f;
    #pragma unroll
    for (int k = 1; k < 16; ++k) {
        wkr[k] = wkr[k-1] * w1r - wki[k-1] * w1i;
        wki[k] = wkr[k-1] * w1i + wki[k-1] * w1r;
    }

    // ---- stage twiddles for cross-lane FFT ----
    float c64[6], s64[6];
    #pragma unroll
    for (int t = 0; t < 6; ++t) {
        const int half = 32 >> t;
        const bool hi = (lane & half) != 0;
        const int jj = (lane & (half - 1)) << (t + 4);
        c64[t] = hi ? twc[jj] : 1.0f;
        s64[t] = hi ? tws[jj] : 0.0f;
    }

    // ---- A) 16-pt DIF FFT in registers ----
    #define CBFLY(ar, ai, br, bi, wr, wi) { \
        const float _tr = (ar) - (br), _ti = (ai) - (bi); \
        (ar) += (br); (ai) += (bi); \
        (br) = _tr * (wr) - _ti * (wi); \
        (bi) = _tr * (wi) + _ti * (wr); }

    #pragma unroll
    for (int p = 0; p < 2; ++p) {
        #pragma unroll
        for (int q = 0; q < 8; ++q) CBFLY(zr[p][q], zi[p][q], zr[p][q+8], zi[p][q+8], W16R[q], W16I[q]);
        #pragma unroll
        for (int g = 0; g < 16; g += 8)
            #pragma unroll
            for (int q = 0; q < 4; ++q) CBFLY(zr[p][g+q], zi[p][g+q], zr[p][g+q+4], zi[p][g+q+4], W16R[2*q], W16I[2*q]);
        #pragma unroll
        for (int g = 0; g < 16; g += 4)
            #pragma unroll
            for (int q = 0; q < 2; ++q) CBFLY(zr[p][g+q], zi[p][g+q], zr[p][g+q+2], zi[p][g+q+2], W16R[4*q], W16I[4*q]);
        #pragma unroll
        for (int g = 0; g < 16; g += 2) CBFLY(zr[p][g], zi[p][g], zr[p][g+1], zi[p][g+1], 1.0f, 0.0f);
    }

    // ---- B) cross twiddle ----
    #pragma unroll
    for (int r = 1; r < 16; ++r) {
        const float c1 = wkr[BREV4[r]];
        const float s1 = wki[BREV4[r]];
        #pragma unroll
        for (int p = 0; p < 2; ++p) {
            const float xr = zr[p][r], xi = zi[p][r];
            zr[p][r] = xr * c1 - xi * s1;
            zi[p][r] = xr * s1 + xi * c1;
        }
    }

    // ---- C) 64-pt DIF FFT across lanes ----
    {
        // xor32 / xor16 on the VALU (permlane swap, sum-form butterfly)
        cstage_sum(zr, zi, (lane & 32) ? -2.0f : 0.0f, c64[0], s64[0],
                   [](float v) { return plsum32(v); });
        cstage_sum(zr, zi, (lane & 16) ? -2.0f : 0.0f, c64[1], s64[1],
                   [](float v) { return plsum16(v); });
        float sg;
        sg = (lane & 8) ? -1.0f : 1.0f;
        cstage(zr, zi, sg, c64[2], s64[2], [](float v) { return dppf<DPP_XOR8>(v); });
        sg = (lane & 4) ? -1.0f : 1.0f;
        cstage(zr, zi, sg, c64[3], s64[3], [](float v) { return __shfl_xor(v, 4); });
        sg = (lane & 2) ? -1.0f : 1.0f;
        cstage(zr, zi, sg, c64[4], s64[4], [](float v) { return dppf<DPP_XOR2>(v); });
        sg = (lane & 1) ? -1.0f : 1.0f;
        cstage(zr, zi, sg, c64[5], s64[5], [](float v) { return dppf<DPP_XOR1>(v); });
    }

    // ---- per pair: separation + magnitude + product write, then mel ----
    const int k2 = (int)(__brev((unsigned)lane) >> 26);
    const int lp0 = (int)(__brev((unsigned)((64 - k2) & 63)) >> 26);
    const int k2m16 = (k2 & 31) * 16;
    const bool hasbin = (k2 < 32);

    #pragma unroll
    for (int p = 0; p < 2; ++p) {
        // separation + magnitude + premultiplied product stores (b64)
        #pragma unroll
        for (int r = 0; r < 16; ++r) {
            float cx, cy;
            if (r == 0) { cx = __shfl(zr[p][0], lp0); cy = __shfl(zi[p][0], lp0); }
            else        { cx = __shfl_xor(zr[p][SIG[r]], 63); cy = __shfl_xor(zi[p][SIG[r]], 63); }
            const float a = zr[p][r], b = zi[p][r];
            const float magA = sqrtf((a + cx) * (a + cx) + (b - cy) * (b - cy));
            const float magB = sqrtf((b + cy) * (b + cy) + (a - cx) * (a - cx));
            if (hasbin) {
                const int sl = swz(k2m16 + BREV4[r]);
                const float2 wt = wtab[sl];
                prodA[w][sl] = make_float2(magA * wt.x, magA * wt.y);
                prodB[w][sl] = make_float2(magB * wt.x, magB * wt.y);
            }
        }

        // triangle mel loop: 1 b64 read per bin, split accumulator
        #pragma unroll
        for (int ii = 0; ii < 3; ++ii) {
            const int t2 = lane + 64 * ii;
            if (t2 < 2 * N_MELS) {
                const int m = 79 - (t2 >> 1);      // descending width order
                const int fi = t2 & 1;
                const float2* P = fi ? prodB[w] : prodA[w];
                const int ka = ks[m], kb = ks[m + 1], kc = ks[m + 2];
                float acc0 = 0.0f, acc1 = 0.0f;
                for (int k = ka; k < kc; k += 2) {
                    const float2 p0 = P[swz(k)];
                    acc0 += (k < kb) ? p0.x : p0.y;
                    const int kn = k + 1;
                    if (kn < kc) {
                        const float2 p1 = P[swz(kn)];
                        acc1 += (kn < kb) ? p1.x : p1.y;
                    }
                }
                const unsigned g = (unsigned)(g0 + 2 * p + fi);
                const unsigned bb = g / NUM_FRAMES;
                const unsigned ff = g - bb * NUM_FRAMES;
                out[((size_t)bb * N_MELS + m) * NUM_FRAMES + ff] = acc0 + acc1;
            }
        }
    }
}

extern "C" void kernel_launch(void* const* d_in, const int* in_sizes, int n_in,
                              void* d_out, int out_size, void* d_ws, size_t ws_size,
                              hipStream_t stream) {
    const float* wav    = (const float*)d_in[0];
    const float* window = (const float*)d_in[1];
    const float* fb     = (const float*)d_in[2];
    const float* cosT   = (const float*)d_in[3];
    const float* sinT   = (const float*)d_in[4];
    float* out = (float*)d_out;

    const int blocks = TOTAL_FRAMES / 16;  // 1251: 4 waves/block, 4 frames/wave
    melspec_prod_kernel<<<blocks, 256, 0, stream>>>(wav, window, fb, cosT, sinT, out);
}